// Round 1
// baseline (22961.861 us; speedup 1.0000x reference)
//
#include <hip/hip_runtime.h>
#include <math.h>

#define D_IN  512
#define HID   1024
#define BATCH 64
#define SEQ   512
#define K3    3072            // 3*HID
#define KTOT  1536            // D_IN + HID
#define KC    128             // K-chunk staged in LDS

// Build WT[c][g][k]: c in [0,1024), g in [0,3), k in [0,1536)
// k < 512  -> W_in[k][g*HID + c]
// k >= 512 -> W_h [k-512][g*HID + c]
__global__ __launch_bounds__(256) void build_wt(const float* __restrict__ Win,
                                                const float* __restrict__ Wh,
                                                float* __restrict__ WT) {
    int idx = blockIdx.x * 256 + threadIdx.x;   // (c,g,k) with k fastest
    if (idx >= HID * 3 * KTOT) return;
    int k  = idx % KTOT;
    int cg = idx / KTOT;
    int g  = cg % 3;
    int c  = cg / 3;
    int col = g * HID + c;
    float v = (k < D_IN) ? Win[(size_t)k * K3 + col]
                         : Wh[(size_t)(k - D_IN) * K3 + col];
    WT[idx] = v;
}

// One GRU timestep. Grid: 256 blocks x 256 threads (4 waves).
// Wave w of block bk owns output column c = bk*4 + w, for all 64 batches (lane = b).
__global__ __launch_bounds__(256) void gru_step(const float* __restrict__ x,
                                                const float* __restrict__ bin,
                                                const float* __restrict__ WT,
                                                float* __restrict__ out,
                                                int t) {
    __shared__ float Asub[KC][BATCH];   // transposed chunk: [kk][b]
    float* hall = out + BATCH * HID;    // h_all (B,S,H) region of d_out

    const int tid  = threadIdx.x;
    const int lane = tid & 63;                                    // batch index
    const int wv   = __builtin_amdgcn_readfirstlane(tid >> 6);    // wave id (scalar)
    const int c    = blockIdx.x * 4 + wv;                         // output column (scalar)
    const float* w0 = WT + (size_t)c * 3 * KTOT;                  // z weights
    const float* w1 = w0 + KTOT;                                  // r weights
    const float* w2 = w1 + KTOT;                                  // n weights

    const int r = tid >> 2;   // staging row 0..63
    const int q = tid & 3;    // staging quad 0..3

    float az = 0.f, ar = 0.f, anx = 0.f, anh = 0.f;

    for (int k0 = 0; k0 < KTOT; k0 += KC) {
        __syncthreads();
        const bool xphase = (k0 < D_IN);   // chunk fully in x-part or h-part (512%128==0)
        if (xphase) {
            const float* src = x + ((size_t)r * SEQ + t) * D_IN + k0;
            #pragma unroll
            for (int i = 0; i < 8; ++i) {
                int kk = q * 4 + i * 16;
                float4 v = *(const float4*)(src + kk);
                Asub[kk + 0][r] = v.x; Asub[kk + 1][r] = v.y;
                Asub[kk + 2][r] = v.z; Asub[kk + 3][r] = v.w;
            }
        } else if (t == 0) {
            #pragma unroll
            for (int i = 0; i < 8; ++i) {
                int kk = q * 4 + i * 16;
                Asub[kk + 0][r] = 0.f; Asub[kk + 1][r] = 0.f;
                Asub[kk + 2][r] = 0.f; Asub[kk + 3][r] = 0.f;
            }
        } else {
            const float* src = hall + ((size_t)r * SEQ + (t - 1)) * HID + (k0 - D_IN);
            #pragma unroll
            for (int i = 0; i < 8; ++i) {
                int kk = q * 4 + i * 16;
                float4 v = *(const float4*)(src + kk);
                Asub[kk + 0][r] = v.x; Asub[kk + 1][r] = v.y;
                Asub[kk + 2][r] = v.z; Asub[kk + 3][r] = v.w;
            }
        }
        __syncthreads();

        const float* wz = w0 + k0;
        const float* wr = w1 + k0;
        const float* wn = w2 + k0;
        if (xphase) {
            #pragma unroll 16
            for (int kk = 0; kk < KC; ++kk) {
                float a = Asub[kk][lane];
                az  = fmaf(a, wz[kk], az);
                ar  = fmaf(a, wr[kk], ar);
                anx = fmaf(a, wn[kk], anx);
            }
        } else {
            #pragma unroll 16
            for (int kk = 0; kk < KC; ++kk) {
                float a = Asub[kk][lane];
                az  = fmaf(a, wz[kk], az);
                ar  = fmaf(a, wr[kk], ar);
                anh = fmaf(a, wn[kk], anh);
            }
        }
    }

    // gates (safe saturating forms: no inf/inf NaNs)
    float bz = bin[c];
    float br = bin[HID + c];
    float bn = bin[2 * HID + c];
    float hprev = (t == 0) ? 0.f
                           : hall[((size_t)lane * SEQ + (t - 1)) * HID + c];
    float z  = 1.f / (1.f + __expf(-(az + bz)));
    float rr = 1.f / (1.f + __expf(-(ar + br)));
    float pre = anx + bn + rr * anh;
    float e2  = __expf(2.f * pre);
    float n   = 1.f - 2.f / (e2 + 1.f);
    float h   = (1.f - z) * n + z * hprev;
    hall[((size_t)lane * SEQ + t) * HID + c] = h;
}

__global__ __launch_bounds__(256) void copy_final(float* __restrict__ out) {
    int idx = blockIdx.x * 256 + threadIdx.x;   // b*HID + c
    if (idx >= BATCH * HID) return;
    int b = idx / HID;
    int c = idx % HID;
    const float* hall = out + BATCH * HID;
    out[idx] = hall[((size_t)b * SEQ + (SEQ - 1)) * HID + c];
}

extern "C" void kernel_launch(void* const* d_in, const int* in_sizes, int n_in,
                              void* d_out, int out_size, void* d_ws, size_t ws_size,
                              hipStream_t stream) {
    const float* x   = (const float*)d_in[0];
    const float* Win = (const float*)d_in[1];
    const float* bin = (const float*)d_in[2];
    const float* Wh  = (const float*)d_in[3];
    float* out = (float*)d_out;
    float* WT  = (float*)d_ws;   // 1024*3*1536*4 = 18.9 MB

    int nwt = HID * 3 * KTOT;
    hipLaunchKernelGGL(build_wt, dim3((nwt + 255) / 256), dim3(256), 0, stream,
                       Win, Wh, WT);
    for (int t = 0; t < SEQ; ++t) {
        hipLaunchKernelGGL(gru_step, dim3(HID / 4), dim3(256), 0, stream,
                           x, bin, WT, out, t);
    }
    hipLaunchKernelGGL(copy_final, dim3(BATCH * HID / 256), dim3(256), 0, stream,
                       out);
}

// Round 2
// 9584.261 us; speedup vs baseline: 2.3958x; 2.3958x over previous
//
#include <hip/hip_runtime.h>
#include <math.h>

#define D_IN   512
#define HID    1024
#define SEQ    512
#define NBATCH 64
#define K3     3072
#define KTOT   1536
#define WB_ELEMS (K3 * KTOT)

typedef __attribute__((ext_vector_type(8))) short short8;
typedef __attribute__((ext_vector_type(4))) float f32x4;

#define MFMA(a, b, c) __builtin_amdgcn_mfma_f32_16x16x32_bf16((a), (b), (c), 0, 0, 0)

// ---------------- build fused transposed weight planes (hi/lo bf16) ----------------
// WBh/WBl: [col 0..3071][k 0..1535], k<512 -> W_in[k][col], k>=512 -> W_h[k-512][col]
__global__ __launch_bounds__(256) void build_wt(const float* __restrict__ Win,
                                                const float* __restrict__ Wh,
                                                __bf16* __restrict__ WBh,
                                                __bf16* __restrict__ WBl) {
    int idx = blockIdx.x * 256 + threadIdx.x;
    if (idx >= WB_ELEMS) return;
    int k   = idx % KTOT;
    int col = idx / KTOT;
    float v = (k < D_IN) ? Win[(size_t)k * K3 + col]
                         : Wh[(size_t)(k - D_IN) * K3 + col];
    __bf16 hi = (__bf16)v;
    WBh[idx] = hi;
    WBl[idx] = (__bf16)(v - (float)hi);
}

// ---------------- one GRU timestep ----------------
// Grid: 256 blocks x 256 threads. Block (mq = bid&3, nb = bid>>2):
//   batches [16*mq, 16*mq+16), column-triples {cb+j, 1024+cb+j, 2048+cb+j}, cb=16*nb.
// Wave w handles K-quarter [384w, 384w+384) and accumulates 4 fragments
// (z, r, n_x, n_h); cross-wave sum via LDS; epilogue computes gates + h.
__global__ __launch_bounds__(256) void gru_step(const float* __restrict__ x,
                                                const float* __restrict__ bin,
                                                const __bf16* __restrict__ WBh,
                                                const __bf16* __restrict__ WBl,
                                                float* __restrict__ out,
                                                int t) {
    __shared__ float red[4][4][4][64];   // [wave][gate][reg][lane]
    float* hall = out + NBATCH * HID;    // h_all (B,S,H) region of d_out

    const int tid = threadIdx.x;
    const int l   = tid & 63;
    const int w   = tid >> 6;
    const int mq  = blockIdx.x & 3;
    const int cb  = (blockIdx.x >> 2) * 16;

    const int m    = mq * 16 + (l & 15);   // batch row this lane feeds into A
    const int koff = (l >> 4) * 8;         // lane k sub-offset within 32-k step

    f32x4 accZ  = {0.f, 0.f, 0.f, 0.f};
    f32x4 accR  = {0.f, 0.f, 0.f, 0.f};
    f32x4 accNX = {0.f, 0.f, 0.f, 0.f};
    f32x4 accNH = {0.f, 0.f, 0.f, 0.f};

    const int colz = cb + (l & 15);
    const int kw0  = w * 384;

    #pragma unroll
    for (int s = 0; s < 12; ++s) {
        const int  ks  = kw0 + s * 32;
        const bool xph = (ks < D_IN);

        // ---- A: 8 fp32 values -> hi/lo bf16 split
        float af0, af1, af2, af3, af4, af5, af6, af7;
        if (xph) {
            const float* ap = x + ((size_t)m * SEQ + t) * D_IN + ks + koff;
            float4 v0 = *(const float4*)ap;
            float4 v1 = *(const float4*)(ap + 4);
            af0 = v0.x; af1 = v0.y; af2 = v0.z; af3 = v0.w;
            af4 = v1.x; af5 = v1.y; af6 = v1.z; af7 = v1.w;
        } else {
            if (t == 0) continue;  // h_{-1} == 0: no contribution
            const float* ap = hall + ((size_t)m * SEQ + (t - 1)) * HID + (ks - D_IN) + koff;
            float4 v0 = *(const float4*)ap;
            float4 v1 = *(const float4*)(ap + 4);
            af0 = v0.x; af1 = v0.y; af2 = v0.z; af3 = v0.w;
            af4 = v1.x; af5 = v1.y; af6 = v1.z; af7 = v1.w;
        }
        short8 ahi, alo;
        {
            float afv[8] = {af0, af1, af2, af3, af4, af5, af6, af7};
            #pragma unroll
            for (int j = 0; j < 8; ++j) {
                __bf16 hb = (__bf16)afv[j];
                __bf16 lb = (__bf16)(afv[j] - (float)hb);
                ahi[j] = __builtin_bit_cast(short, hb);
                alo[j] = __builtin_bit_cast(short, lb);
            }
        }

        // ---- B: 3 gate columns x {hi, lo}
        const size_t o0 = (size_t)colz * KTOT + ks + koff;
        const size_t o1 = (size_t)(colz + HID) * KTOT + ks + koff;
        const size_t o2 = (size_t)(colz + 2 * HID) * KTOT + ks + koff;
        short8 bzh = *(const short8*)(WBh + o0);
        short8 brh = *(const short8*)(WBh + o1);
        short8 bnh = *(const short8*)(WBh + o2);
        short8 bzl = *(const short8*)(WBl + o0);
        short8 brl = *(const short8*)(WBl + o1);
        short8 bnl = *(const short8*)(WBl + o2);

        // ---- 9 MFMAs: (ahi+alo)(bhi+blo) minus lo*lo
        accZ = MFMA(ahi, bzh, accZ);
        accZ = MFMA(ahi, bzl, accZ);
        accZ = MFMA(alo, bzh, accZ);
        accR = MFMA(ahi, brh, accR);
        accR = MFMA(ahi, brl, accR);
        accR = MFMA(alo, brh, accR);
        if (xph) {
            accNX = MFMA(ahi, bnh, accNX);
            accNX = MFMA(ahi, bnl, accNX);
            accNX = MFMA(alo, bnh, accNX);
        } else {
            accNH = MFMA(ahi, bnh, accNH);
            accNH = MFMA(ahi, bnl, accNH);
            accNH = MFMA(alo, bnh, accNH);
        }
    }

    // ---- cross-wave reduction via LDS
    #pragma unroll
    for (int r = 0; r < 4; ++r) {
        red[w][0][r][l] = accZ[r];
        red[w][1][r][l] = accR[r];
        red[w][2][r][l] = accNX[r];
        red[w][3][r][l] = accNH[r];
    }
    __syncthreads();

    const int r2 = tid >> 6;
    const int l2 = tid & 63;
    float sz = 0.f, sr = 0.f, snx = 0.f, snh = 0.f;
    #pragma unroll
    for (int wv = 0; wv < 4; ++wv) {
        sz  += red[wv][0][r2][l2];
        sr  += red[wv][1][r2][l2];
        snx += red[wv][2][r2][l2];
        snh += red[wv][3][r2][l2];
    }

    // C layout: col = lane&15, row = (lane>>4)*4 + reg   [m89-verified]
    const int b = mq * 16 + (l2 >> 4) * 4 + r2;
    const int c = cb + (l2 & 15);

    float z   = 1.f / (1.f + __expf(-(sz + bin[c])));
    float rr  = 1.f / (1.f + __expf(-(sr + bin[HID + c])));
    float pre = snx + bin[2 * HID + c] + rr * snh;
    float e2  = __expf(2.f * pre);
    float n   = 1.f - 2.f / (e2 + 1.f);
    float hprev = (t == 0) ? 0.f : hall[((size_t)b * SEQ + (t - 1)) * HID + c];
    float h = (1.f - z) * n + z * hprev;
    hall[((size_t)b * SEQ + t) * HID + c] = h;
}

__global__ __launch_bounds__(256) void copy_final(float* __restrict__ out) {
    int idx = blockIdx.x * 256 + threadIdx.x;   // b*HID + c
    if (idx >= NBATCH * HID) return;
    int b = idx / HID;
    int c = idx % HID;
    const float* hall = out + NBATCH * HID;
    out[idx] = hall[((size_t)b * SEQ + (SEQ - 1)) * HID + c];
}

extern "C" void kernel_launch(void* const* d_in, const int* in_sizes, int n_in,
                              void* d_out, int out_size, void* d_ws, size_t ws_size,
                              hipStream_t stream) {
    const float* x   = (const float*)d_in[0];
    const float* Win = (const float*)d_in[1];
    const float* bin = (const float*)d_in[2];
    const float* Wh  = (const float*)d_in[3];
    float* out = (float*)d_out;

    __bf16* WBh = (__bf16*)d_ws;                       // 9.44 MB
    __bf16* WBl = (__bf16*)d_ws + (size_t)WB_ELEMS;    // 9.44 MB

    hipLaunchKernelGGL(build_wt, dim3((WB_ELEMS + 255) / 256), dim3(256), 0, stream,
                       Win, Wh, WBh, WBl);
    for (int t = 0; t < SEQ; ++t) {
        hipLaunchKernelGGL(gru_step, dim3(256), dim3(256), 0, stream,
                           x, bin, WBh, WBl, out, t);
    }
    hipLaunchKernelGGL(copy_final, dim3(NBATCH * HID / 256), dim3(256), 0, stream,
                       out);
}

// Round 3
// 6532.168 us; speedup vs baseline: 3.5152x; 1.4672x over previous
//
#include <hip/hip_runtime.h>
#include <math.h>

#define D_IN   512
#define HID    1024
#define SEQ    512
#define NBATCH 64
#define K3     3072
#define KTOT   1536
#define WB_ELEMS (K3 * KTOT)

typedef __attribute__((ext_vector_type(8))) short short8;
typedef __attribute__((ext_vector_type(4))) float f32x4;

#define MFMA(a, b, c) __builtin_amdgcn_mfma_f32_16x16x32_bf16((a), (b), (c), 0, 0, 0)

// ---------------- build fused transposed weight planes (hi/lo bf16) ----------------
// WBh/WBl: [col 0..3071][k 0..1535], k<512 -> W_in[k][col], k>=512 -> W_h[k-512][col]
__global__ __launch_bounds__(256) void build_wt(const float* __restrict__ Win,
                                                const float* __restrict__ Wh,
                                                __bf16* __restrict__ WBh,
                                                __bf16* __restrict__ WBl) {
    int idx = blockIdx.x * 256 + threadIdx.x;
    if (idx >= WB_ELEMS) return;
    int k   = idx % KTOT;
    int col = idx / KTOT;
    float v = (k < D_IN) ? Win[(size_t)k * K3 + col]
                         : Wh[(size_t)(k - D_IN) * K3 + col];
    __bf16 hi = (__bf16)v;
    WBh[idx] = hi;
    WBl[idx] = (__bf16)(v - (float)hi);
}

// ---------------- one GRU timestep ----------------
// Grid: 256 blocks x 512 threads (8 waves).
// XCD-sharer swizzle: x = bid&7 (XCD), j = bid>>3; nb = x + 8*(j>>2); mq = j&3.
//   -> each XCD hosts nb ≡ x (mod 8) with ALL 4 mq sharers: weight slice
//      (8 x 294KB = 2.3MB) is L2-resident; 4x dup reads become L2 hits.
// Block (mq, nb): batches [16mq,16mq+16), column-triples {cb+j, 1024+cb+j, 2048+cb+j}.
// Wave w: K-range [192w, 192w+192), 6 s-iters of 32. 8-way LDS reduction + epilogue.
__global__ __launch_bounds__(512) void gru_step(const float* __restrict__ x,
                                                const float* __restrict__ bin,
                                                const __bf16* __restrict__ WBh,
                                                const __bf16* __restrict__ WBl,
                                                float* __restrict__ out,
                                                int t) {
    __shared__ float red[8][4][4][64];   // [wave][gate][reg][lane] = 32KB
    float* hall = out + NBATCH * HID;    // h_all (B,S,H) region of d_out

    const int tid = threadIdx.x;
    const int l   = tid & 63;
    const int w   = tid >> 6;                 // 0..7
    const int xcd = blockIdx.x & 7;
    const int j   = blockIdx.x >> 3;
    const int nb  = xcd + 8 * (j >> 2);       // 0..63
    const int mq  = j & 3;                    // 0..3
    const int cb  = nb * 16;

    const int m    = mq * 16 + (l & 15);      // batch row this lane feeds into A
    const int koff = (l >> 4) * 8;            // lane k sub-offset within 32-k step

    f32x4 accZ  = {0.f, 0.f, 0.f, 0.f};
    f32x4 accR  = {0.f, 0.f, 0.f, 0.f};
    f32x4 accNX = {0.f, 0.f, 0.f, 0.f};
    f32x4 accNH = {0.f, 0.f, 0.f, 0.f};

    const int colz = cb + (l & 15);
    const int kw0  = w * 192;

    #pragma unroll
    for (int s = 0; s < 6; ++s) {
        const int  ks  = kw0 + s * 32;
        const bool xph = (ks < D_IN);

        // ---- A: 8 fp32 values -> hi/lo bf16 split
        float afv[8];
        if (xph) {
            const float* ap = x + ((size_t)m * SEQ + t) * D_IN + ks + koff;
            float4 v0 = *(const float4*)ap;
            float4 v1 = *(const float4*)(ap + 4);
            afv[0] = v0.x; afv[1] = v0.y; afv[2] = v0.z; afv[3] = v0.w;
            afv[4] = v1.x; afv[5] = v1.y; afv[6] = v1.z; afv[7] = v1.w;
        } else {
            if (t == 0) continue;  // h_{-1} == 0: no contribution
            const float* ap = hall + ((size_t)m * SEQ + (t - 1)) * HID + (ks - D_IN) + koff;
            float4 v0 = *(const float4*)ap;
            float4 v1 = *(const float4*)(ap + 4);
            afv[0] = v0.x; afv[1] = v0.y; afv[2] = v0.z; afv[3] = v0.w;
            afv[4] = v1.x; afv[5] = v1.y; afv[6] = v1.z; afv[7] = v1.w;
        }
        short8 ahi, alo;
        #pragma unroll
        for (int jj = 0; jj < 8; ++jj) {
            __bf16 hb = (__bf16)afv[jj];
            __bf16 lb = (__bf16)(afv[jj] - (float)hb);
            ahi[jj] = __builtin_bit_cast(short, hb);
            alo[jj] = __builtin_bit_cast(short, lb);
        }

        // ---- B: 3 gate columns x {hi, lo}
        const size_t o0 = (size_t)colz * KTOT + ks + koff;
        const size_t o1 = (size_t)(colz + HID) * KTOT + ks + koff;
        const size_t o2 = (size_t)(colz + 2 * HID) * KTOT + ks + koff;
        short8 bzh = *(const short8*)(WBh + o0);
        short8 brh = *(const short8*)(WBh + o1);
        short8 bnh = *(const short8*)(WBh + o2);
        short8 bzl = *(const short8*)(WBl + o0);
        short8 brl = *(const short8*)(WBl + o1);
        short8 bnl = *(const short8*)(WBl + o2);

        // ---- 9 MFMAs: (ahi+alo)(bhi+blo) minus lo*lo
        accZ = MFMA(ahi, bzh, accZ);
        accZ = MFMA(ahi, bzl, accZ);
        accZ = MFMA(alo, bzh, accZ);
        accR = MFMA(ahi, brh, accR);
        accR = MFMA(ahi, brl, accR);
        accR = MFMA(alo, brh, accR);
        if (xph) {
            accNX = MFMA(ahi, bnh, accNX);
            accNX = MFMA(ahi, bnl, accNX);
            accNX = MFMA(alo, bnh, accNX);
        } else {
            accNH = MFMA(ahi, bnh, accNH);
            accNH = MFMA(ahi, bnl, accNH);
            accNH = MFMA(alo, bnh, accNH);
        }
    }

    // ---- cross-wave reduction via LDS
    #pragma unroll
    for (int r = 0; r < 4; ++r) {
        red[w][0][r][l] = accZ[r];
        red[w][1][r][l] = accR[r];
        red[w][2][r][l] = accNX[r];
        red[w][3][r][l] = accNH[r];
    }
    __syncthreads();

    if (tid < 256) {
        const int r2 = tid >> 6;
        const int l2 = tid & 63;
        float sz = 0.f, sr = 0.f, snx = 0.f, snh = 0.f;
        #pragma unroll
        for (int wv = 0; wv < 8; ++wv) {
            sz  += red[wv][0][r2][l2];
            sr  += red[wv][1][r2][l2];
            snx += red[wv][2][r2][l2];
            snh += red[wv][3][r2][l2];
        }

        // C layout: col = lane&15, row = (lane>>4)*4 + reg   [m89-verified]
        const int b = mq * 16 + (l2 >> 4) * 4 + r2;
        const int c = cb + (l2 & 15);

        float z   = 1.f / (1.f + __expf(-(sz + bin[c])));
        float rr  = 1.f / (1.f + __expf(-(sr + bin[HID + c])));
        float pre = snx + bin[2 * HID + c] + rr * snh;
        float e2  = __expf(2.f * pre);
        float n   = 1.f - 2.f / (e2 + 1.f);
        float hprev = (t == 0) ? 0.f : hall[((size_t)b * SEQ + (t - 1)) * HID + c];
        float h = (1.f - z) * n + z * hprev;
        hall[((size_t)b * SEQ + t) * HID + c] = h;
    }
}

__global__ __launch_bounds__(256) void copy_final(float* __restrict__ out) {
    int idx = blockIdx.x * 256 + threadIdx.x;   // b*HID + c
    if (idx >= NBATCH * HID) return;
    int b = idx / HID;
    int c = idx % HID;
    const float* hall = out + NBATCH * HID;
    out[idx] = hall[((size_t)b * SEQ + (SEQ - 1)) * HID + c];
}

extern "C" void kernel_launch(void* const* d_in, const int* in_sizes, int n_in,
                              void* d_out, int out_size, void* d_ws, size_t ws_size,
                              hipStream_t stream) {
    const float* x   = (const float*)d_in[0];
    const float* Win = (const float*)d_in[1];
    const float* bin = (const float*)d_in[2];
    const float* Wh  = (const float*)d_in[3];
    float* out = (float*)d_out;

    __bf16* WBh = (__bf16*)d_ws;                       // 9.44 MB
    __bf16* WBl = (__bf16*)d_ws + (size_t)WB_ELEMS;    // 9.44 MB

    hipLaunchKernelGGL(build_wt, dim3((WB_ELEMS + 255) / 256), dim3(256), 0, stream,
                       Win, Wh, WBh, WBl);
    for (int t = 0; t < SEQ; ++t) {
        hipLaunchKernelGGL(gru_step, dim3(256), dim3(512), 0, stream,
                           x, bin, WBh, WBl, out, t);
    }
    hipLaunchKernelGGL(copy_final, dim3(NBATCH * HID / 256), dim3(256), 0, stream,
                       out);
}